// Round 1
// baseline (168.331 us; speedup 1.0000x reference)
//
#include <hip/hip_runtime.h>

// Problem constants (from reference setup_inputs): B=16, C=4, H=W=1024.
#define B_  16
#define H_  1024
#define W_  1024
#define OW_ (2 * W_)       // 2048
#define OH_ (2 * H_)       // 2048

__global__ __launch_bounds__(256) void unsqueeze_cons_kernel(
    const float* __restrict__ in,
    float* __restrict__ out_x,
    float* __restrict__ out_cons)
{
    // One thread per (b, r, c4) where c4 indexes groups of 4 input columns.
    // Block = 256 threads -> within a block only c4 varies (W/4 = 256),
    // so b and r are block-uniform and the b==0 branch is non-divergent.
    const long tid = (long)blockIdx.x * blockDim.x + threadIdx.x;
    const int c4 = (int)(tid & (W_ / 4 - 1));        // 0..255
    const int r  = (int)((tid >> 8) & (H_ - 1));     // 0..1023
    const int b  = (int)(tid >> 18);                 // 0..15

    const long chanStride = (long)H_ * W_;           // 1,048,576
    const long base = ((long)b * 4) * chanStride + (long)r * W_ + (long)c4 * 4;

    const float4 ch0 = *reinterpret_cast<const float4*>(in + base);
    const float4 ch1 = *reinterpret_cast<const float4*>(in + base + chanStride);
    const float4 ch2 = *reinterpret_cast<const float4*>(in + base + 2 * chanStride);
    const float4 ch3 = *reinterpret_cast<const float4*>(in + base + 3 * chanStride);

    // ---- output 0: pixel-shuffle ----
    // out_x[b, 2r+dr, 2c+dc] = in[b, dr+2*dc, r, c]
    // row 2r   : ch0 (dc=0) interleaved with ch2 (dc=1)
    // row 2r+1 : ch1 interleaved with ch3
    const long orow0 = (long)b * OH_ * OW_ + (long)(2 * r) * OW_ + (long)c4 * 8;
    const long orow1 = orow0 + OW_;

    float4 x00 = {ch0.x, ch2.x, ch0.y, ch2.y};
    float4 x01 = {ch0.z, ch2.z, ch0.w, ch2.w};
    float4 x10 = {ch1.x, ch3.x, ch1.y, ch3.y};
    float4 x11 = {ch1.z, ch3.z, ch1.w, ch3.w};
    *reinterpret_cast<float4*>(out_x + orow0)     = x00;
    *reinterpret_cast<float4*>(out_x + orow0 + 4) = x01;
    *reinterpret_cast<float4*>(out_x + orow1)     = x10;
    *reinterpret_cast<float4*>(out_x + orow1 + 4) = x11;

    // ---- output 1: cons plane (from batch-0 channels), broadcast over b ----
    float4 a0, a1, a2;
    if (b == 0) {          // block-uniform branch; reuse this thread's loads
        a0 = ch0; a1 = ch1; a2 = ch2;
    } else {               // batch-0 channels: 12 MiB working set, L2/L3-resident
        const long base0 = (long)r * W_ + (long)c4 * 4;
        a0 = *reinterpret_cast<const float4*>(in + base0);
        a1 = *reinterpret_cast<const float4*>(in + base0 + chanStride);
        a2 = *reinterpret_cast<const float4*>(in + base0 + 2 * chanStride);
    }

    const float k3 = 1.0f / 3.0f;
    float4 s2, s1, s0;
    s2.x = (a0.x + 1.0f) * 0.5f;
    s2.y = (a0.y + 1.0f) * 0.5f;
    s2.z = (a0.z + 1.0f) * 0.5f;
    s2.w = (a0.w + 1.0f) * 0.5f;
    s1.x = (a0.x + a1.x + 1.0f) * k3;
    s1.y = (a0.y + a1.y + 1.0f) * k3;
    s1.z = (a0.z + a1.z + 1.0f) * k3;
    s1.w = (a0.w + a1.w + 1.0f) * k3;
    s0.x = (a0.x + a1.x + a2.x + 1.0f) * 0.25f;
    s0.y = (a0.y + a1.y + a2.y + 1.0f) * 0.25f;
    s0.z = (a0.z + a1.z + a2.z + 1.0f) * 0.25f;
    s0.w = (a0.w + a1.w + a2.w + 1.0f) * 0.25f;

    // cons row 2r   : (2c)->1.0 (s3), (2c+1)->s1
    // cons row 2r+1 : (2c)->s2,       (2c+1)->s0
    float4 c00 = {1.0f, s1.x, 1.0f, s1.y};
    float4 c01 = {1.0f, s1.z, 1.0f, s1.w};
    float4 c10 = {s2.x, s0.x, s2.y, s0.y};
    float4 c11 = {s2.z, s0.z, s2.w, s0.w};
    *reinterpret_cast<float4*>(out_cons + orow0)     = c00;
    *reinterpret_cast<float4*>(out_cons + orow0 + 4) = c01;
    *reinterpret_cast<float4*>(out_cons + orow1)     = c10;
    *reinterpret_cast<float4*>(out_cons + orow1 + 4) = c11;
}

extern "C" void kernel_launch(void* const* d_in, const int* in_sizes, int n_in,
                              void* d_out, int out_size, void* d_ws, size_t ws_size,
                              hipStream_t stream) {
    const float* in = (const float*)d_in[0];
    float* out_x    = (float*)d_out;                                   // (16,1,2048,2048)
    float* out_cons = (float*)d_out + (long)B_ * OH_ * OW_;            // (16,1,2048,2048)

    const long total_threads = (long)B_ * H_ * (W_ / 4);               // 4,194,304
    const int block = 256;
    const int grid = (int)(total_threads / block);                     // 16,384
    unsqueeze_cons_kernel<<<grid, block, 0, stream>>>(in, out_x, out_cons);
}

// Round 2
// 163.620 us; speedup vs baseline: 1.0288x; 1.0288x over previous
//
#include <hip/hip_runtime.h>

// Problem constants (from reference setup_inputs): B=16, C=4, H=W=1024.
#define B_  16
#define H_  1024
#define W_  1024
#define OW_ (2 * W_)       // 2048
#define OH_ (2 * H_)       // 2048

__global__ __launch_bounds__(256) void unsqueeze_cons_kernel(
    const float* __restrict__ in,
    float* __restrict__ out_x,
    float* __restrict__ out_cons)
{
    // One thread per (b, r, c2); c2 indexes groups of 2 input columns
    // (= 4 output columns). Every store instruction is fully contiguous
    // across the wave: lane stride 16 B. Loads are float2 (8 B/lane),
    // also fully coalesced.
    const long tid = (long)blockIdx.x * blockDim.x + threadIdx.x;
    const int c2 = (int)(tid & (W_ / 2 - 1));        // 0..511
    const int r  = (int)((tid >> 9) & (H_ - 1));     // 0..1023
    const int b  = (int)(tid >> 19);                 // 0..15

    const long chanStride = (long)H_ * W_;           // 1,048,576
    const long base = ((long)b * 4) * chanStride + (long)r * W_ + (long)c2 * 2;

    const float2 ch0 = *reinterpret_cast<const float2*>(in + base);
    const float2 ch1 = *reinterpret_cast<const float2*>(in + base + chanStride);
    const float2 ch2 = *reinterpret_cast<const float2*>(in + base + 2 * chanStride);
    const float2 ch3 = *reinterpret_cast<const float2*>(in + base + 3 * chanStride);

    // ---- output 0: pixel-shuffle ----
    // out_x[b, 2r+dr, 2c+dc] = in[b, dr+2*dc, r, c]
    // row 2r   : ch0 (dc=0) interleaved with ch2 (dc=1)
    // row 2r+1 : ch1 interleaved with ch3
    const long orow0 = (long)b * OH_ * OW_ + (long)(2 * r) * OW_ + (long)c2 * 4;
    const long orow1 = orow0 + OW_;

    float4 x0 = {ch0.x, ch2.x, ch0.y, ch2.y};
    float4 x1 = {ch1.x, ch3.x, ch1.y, ch3.y};
    *reinterpret_cast<float4*>(out_x + orow0) = x0;
    *reinterpret_cast<float4*>(out_x + orow1) = x1;

    // ---- output 1: cons plane (from batch-0 channels), broadcast over b ----
    float2 a0, a1, a2;
    if (b == 0) {          // block-uniform branch; reuse this thread's loads
        a0 = ch0; a1 = ch1; a2 = ch2;
    } else {               // batch-0 channels: 12 MiB working set, L2/L3-resident
        const long base0 = (long)r * W_ + (long)c2 * 2;
        a0 = *reinterpret_cast<const float2*>(in + base0);
        a1 = *reinterpret_cast<const float2*>(in + base0 + chanStride);
        a2 = *reinterpret_cast<const float2*>(in + base0 + 2 * chanStride);
    }

    const float k3 = 1.0f / 3.0f;
    float2 s2, s1, s0;
    s2.x = (a0.x + 1.0f) * 0.5f;
    s2.y = (a0.y + 1.0f) * 0.5f;
    s1.x = (a0.x + a1.x + 1.0f) * k3;
    s1.y = (a0.y + a1.y + 1.0f) * k3;
    s0.x = (a0.x + a1.x + a2.x + 1.0f) * 0.25f;
    s0.y = (a0.y + a1.y + a2.y + 1.0f) * 0.25f;

    // cons row 2r   : (2c)->1.0 (s3), (2c+1)->s1
    // cons row 2r+1 : (2c)->s2,       (2c+1)->s0
    float4 c0 = {1.0f, s1.x, 1.0f, s1.y};
    float4 c1 = {s2.x, s0.x, s2.y, s0.y};
    *reinterpret_cast<float4*>(out_cons + orow0) = c0;
    *reinterpret_cast<float4*>(out_cons + orow1) = c1;
}

extern "C" void kernel_launch(void* const* d_in, const int* in_sizes, int n_in,
                              void* d_out, int out_size, void* d_ws, size_t ws_size,
                              hipStream_t stream) {
    const float* in = (const float*)d_in[0];
    float* out_x    = (float*)d_out;                                   // (16,1,2048,2048)
    float* out_cons = (float*)d_out + (long)B_ * OH_ * OW_;            // (16,1,2048,2048)

    const long total_threads = (long)B_ * H_ * (W_ / 2);               // 8,388,608
    const int block = 256;
    const int grid = (int)(total_threads / block);                     // 32,768
    unsqueeze_cons_kernel<<<grid, block, 0, stream>>>(in, out_x, out_cons);
}